// Round 7
// baseline (267.578 us; speedup 1.0000x reference)
//
#include <hip/hip_runtime.h>
#include <hip/hip_bf16.h>
#include <stdint.h>

typedef __attribute__((ext_vector_type(8))) short short8;
typedef __attribute__((ext_vector_type(4))) float floatx4;

// ---------------- db4 filter constants ----------------
__device__ __constant__ float c_DL[8] = {
    -0.010597401784997278f, 0.032883011666982945f, 0.030841381835986965f,
    -0.18703481171888114f, -0.02798376941698385f, 0.6308807679295904f,
    0.7148465705525415f, 0.23037781330885523f};
__device__ __constant__ float c_DH[8] = {
    -0.23037781330885523f, 0.7148465705525415f, -0.6308807679295904f,
    -0.02798376941698385f, 0.18703481171888114f, 0.030841381835986965f,
    -0.032883011666982945f, -0.010597401784997278f};
// REC_LO = reverse(DEC_LO)
__device__ __constant__ float c_RL[8] = {
    0.23037781330885523f, 0.7148465705525415f, 0.6308807679295904f,
    -0.02798376941698385f, -0.18703481171888114f, 0.030841381835986965f,
    0.032883011666982945f, -0.010597401784997278f};
__device__ __constant__ float c_RH[8] = {
    -0.010597401784997278f, -0.032883011666982945f, 0.030841381835986965f,
    0.18703481171888114f, -0.02798376941698385f, -0.6308807679295904f,
    0.7148465705525415f, -0.23037781330885523f};

__device__ __forceinline__ float bflo(uint32_t u) { return __uint_as_float(u << 16); }
__device__ __forceinline__ float bfhi(uint32_t u) { return __uint_as_float(u & 0xffff0000u); }
__device__ __forceinline__ float bfu(unsigned short u) { return __uint_as_float(((uint32_t)u) << 16); }
__device__ __forceinline__ short f2bs(float f) {
  __hip_bfloat16 h = __float2bfloat16(f);
  return *reinterpret_cast<short*>(&h);
}

__device__ __forceinline__ int reflect_idx(int t, int n) {
  if (t < 0) t = -1 - t;
  if (t >= n) t = 2 * n - 1 - t;
  return t;
}

// Row strides (padded for aligned vector access)
#define S1R 4100
#define S2R 2056

// ---------------- Weight transpose: w[i][o][p] -> wt[p][i*64+o]
__global__ __launch_bounds__(256) void k_wT(const float* __restrict__ w1,
                                            const float* __restrict__ w2,
                                            float* __restrict__ wt1,
                                            float* __restrict__ wt2) {
  const float* w = blockIdx.z ? w2 : w1;
  float* wt = blockIdx.z ? wt2 : wt1;
  const int io0 = blockIdx.x * 64;
  const int p0 = blockIdx.y * 64;
  const int pw = min(64, 518 - p0);
  const int tid = threadIdx.x;
  __shared__ float ts[64 * 65];
  for (int idx = tid; idx < 64 * 64; idx += 256) {
    int row = idx >> 6, col = idx & 63;
    if (col < pw) ts[row * 65 + col] = w[(size_t)(io0 + row) * 518 + p0 + col];
  }
  __syncthreads();
  for (int idx = tid; idx < 64 * 64; idx += 256) {
    int pl = idx >> 6, io = idx & 63;
    if (pl < pw) wt[(size_t)(p0 + pl) * 4096 + io0 + io] = ts[io * 65 + pl];
  }
}

// ---------------- Level-1 DWT: x (B,N,C) fp32 -> a1,d1 (B*C, stride 4100) bf16
#define NT1 134
#define XTS 138
__global__ __launch_bounds__(256) void k_dwt_first(const float* __restrict__ x,
                                                   __hip_bfloat16* __restrict__ outa,
                                                   __hip_bfloat16* __restrict__ outd) {
  const int b = blockIdx.y;
  const int k0 = blockIdx.x * 64;
  const int tid = threadIdx.x;
  __shared__ float xs[64 * XTS];  // xs[c][nrow]

  const float4* x4 = (const float4*)x;
  for (int idx = tid; idx < NT1 * 16; idx += 256) {
    int nl = idx >> 4, cq = idx & 15;
    int t = 2 * k0 - 6 + nl;
    int n = reflect_idx(t, 8192);
    float4 v = x4[((size_t)b * 8192 + n) * 16 + cq];
    xs[(4 * cq + 0) * XTS + nl] = v.x;
    xs[(4 * cq + 1) * XTS + nl] = v.y;
    xs[(4 * cq + 2) * XTS + nl] = v.z;
    xs[(4 * cq + 3) * XTS + nl] = v.w;
  }
  __syncthreads();

  const int kk = tid & 63;
  const int k = k0 + kk;
  if (k >= 4099) return;
  for (int c = (tid >> 6); c < 64; c += 4) {
    const float2* p = (const float2*)&xs[c * XTS + 2 * kk];
    float2 p0 = p[0], p1 = p[1], p2 = p[2], p3 = p[3];
    float lo = c_DL[0] * p3.y + c_DL[1] * p3.x + c_DL[2] * p2.y + c_DL[3] * p2.x +
               c_DL[4] * p1.y + c_DL[5] * p1.x + c_DL[6] * p0.y + c_DL[7] * p0.x;
    float hi = c_DH[0] * p3.y + c_DH[1] * p3.x + c_DH[2] * p2.y + c_DH[3] * p2.x +
               c_DH[4] * p1.y + c_DH[5] * p1.x + c_DH[6] * p0.y + c_DH[7] * p0.x;
    size_t s = (size_t)b * 64 + c;
    outa[s * S1R + k] = __float2bfloat16(lo);
    outd[s * S1R + k] = __float2bfloat16(hi);
  }
}

// ---------------- Fused analysis levels 2..4, one row per block
__global__ __launch_bounds__(256) void k_ana234(const __hip_bfloat16* __restrict__ a1,
                                                __hip_bfloat16* __restrict__ d2o,
                                                float* __restrict__ d3o,
                                                float* __restrict__ a4o,
                                                float* __restrict__ d4o) {
  const int bid = blockIdx.x;
  const int s = (bid & 7) * 256 + (bid >> 3);  // bijective, XCD-contiguous s-range
  const int i_ch = s >> 5;
  const int bb = s & 31;
  const int r = bb * 64 + i_ch;
  const int tid = threadIdx.x;
  __shared__ float s1[4100];
  __shared__ float s2[2054];
  __shared__ float s3[1032];

  const uint2* row2 = (const uint2*)(a1 + (size_t)r * S1R);
  for (int i = tid; i < 1025; i += 256) {
    uint2 u = row2[i];
    int e = 4 * i;
    s1[e] = bflo(u.x); s1[e + 1] = bfhi(u.x);
    s1[e + 2] = bflo(u.y); s1[e + 3] = bfhi(u.y);
  }
  __syncthreads();

  // level 2: n=4099 -> m=2053
  for (int k = tid; k < 2053; k += 256) {
    float lo = 0.f, hi = 0.f;
    if (k >= 3 && k <= 2048) {
      const float2* p = (const float2*)&s1[2 * k - 6];
      float2 v0 = p[0], v1 = p[1], v2 = p[2], v3 = p[3];
      lo = c_RL[0]*v0.x + c_RL[1]*v0.y + c_RL[2]*v1.x + c_RL[3]*v1.y +
           c_RL[4]*v2.x + c_RL[5]*v2.y + c_RL[6]*v3.x + c_RL[7]*v3.y;
      hi = c_RH[0]*v0.x + c_RH[1]*v0.y + c_RH[2]*v1.x + c_RH[3]*v1.y +
           c_RH[4]*v2.x + c_RH[5]*v2.y + c_RH[6]*v3.x + c_RH[7]*v3.y;
    } else {
#pragma unroll
      for (int j = 0; j < 8; ++j) {
        float v = s1[reflect_idx(2 * k + 1 - j, 4099)];
        lo += c_DL[j] * v; hi += c_DH[j] * v;
      }
    }
    d2o[(size_t)r * S2R + k] = __float2bfloat16(hi);
    s2[k] = lo;
  }
  __syncthreads();

  // level 3: n=2053 -> m=1030
  for (int k = tid; k < 1030; k += 256) {
    float lo = 0.f, hi = 0.f;
    if (k >= 3 && k <= 1025) {
      const float2* p = (const float2*)&s2[2 * k - 6];
      float2 v0 = p[0], v1 = p[1], v2 = p[2], v3 = p[3];
      lo = c_RL[0]*v0.x + c_RL[1]*v0.y + c_RL[2]*v1.x + c_RL[3]*v1.y +
           c_RL[4]*v2.x + c_RL[5]*v2.y + c_RL[6]*v3.x + c_RL[7]*v3.y;
      hi = c_RH[0]*v0.x + c_RH[1]*v0.y + c_RH[2]*v1.x + c_RH[3]*v1.y +
           c_RH[4]*v2.x + c_RH[5]*v2.y + c_RH[6]*v3.x + c_RH[7]*v3.y;
    } else {
#pragma unroll
      for (int j = 0; j < 8; ++j) {
        float v = s2[reflect_idx(2 * k + 1 - j, 2053)];
        lo += c_DL[j] * v; hi += c_DH[j] * v;
      }
    }
    d3o[(size_t)r * 1030 + k] = hi;
    s3[k] = lo;
  }
  __syncthreads();

  // level 4: n=1030 -> m=518, transposed scatter (merged in per-XCD L2)
  for (int k = tid; k < 518; k += 256) {
    float lo = 0.f, hi = 0.f;
    if (k >= 3 && k <= 514) {
      const float2* p = (const float2*)&s3[2 * k - 6];
      float2 v0 = p[0], v1 = p[1], v2 = p[2], v3 = p[3];
      lo = c_RL[0]*v0.x + c_RL[1]*v0.y + c_RL[2]*v1.x + c_RL[3]*v1.y +
           c_RL[4]*v2.x + c_RL[5]*v2.y + c_RL[6]*v3.x + c_RL[7]*v3.y;
      hi = c_RH[0]*v0.x + c_RH[1]*v0.y + c_RH[2]*v1.x + c_RH[3]*v1.y +
           c_RH[4]*v2.x + c_RH[5]*v2.y + c_RH[6]*v3.x + c_RH[7]*v3.y;
    } else {
#pragma unroll
      for (int j = 0; j < 8; ++j) {
        float v = s3[reflect_idx(2 * k + 1 - j, 1030)];
        lo += c_DL[j] * v; hi += c_DH[j] * v;
      }
    }
    a4o[(size_t)k * 2048 + s] = lo;
    d4o[(size_t)k * 2048 + s] = hi;
  }
}

// ---------------- Channel mixing: one block per (p, a-or-d), all staging contiguous.
__global__ __launch_bounds__(256) void k_mix_pc(const float* __restrict__ wt1,
                                                const float* __restrict__ wt2,
                                                const float* __restrict__ a4t,
                                                const float* __restrict__ d4t,
                                                float* __restrict__ am,
                                                float* __restrict__ dm) {
  const int bx = blockIdx.x;
  const int xcd = bx & 7;
  const int j = bx >> 3;
  const int p = (xcd < 6) ? (xcd * 65 + j) : (390 + (xcd - 6) * 64 + j);

  const float* w = blockIdx.y ? wt2 : wt1;
  const float* act = blockIdx.y ? d4t : a4t;
  float* outp = blockIdx.y ? dm : am;

  __shared__ float ws[4096];   // ws[i*64+o]
  __shared__ float as_[2048];  // as_[i*32+b]
  const int tid = threadIdx.x;

  const float4* wg = (const float4*)(w + (size_t)p * 4096);
  const float4* ag = (const float4*)(act + (size_t)p * 2048);
  float4* ws4 = (float4*)ws;
  float4* as4 = (float4*)as_;
  for (int t = tid; t < 1024; t += 256) ws4[t] = wg[t];
  for (int t = tid; t < 512; t += 256) as4[t] = ag[t];
  __syncthreads();

  const int o0 = (tid & 15) * 4;
  const int bq = tid >> 4;
  floatx4 acc0 = {0.f, 0.f, 0.f, 0.f}, acc1 = {0.f, 0.f, 0.f, 0.f};

#pragma unroll 8
  for (int i = 0; i < 64; ++i) {
    floatx4 wv = *(const floatx4*)&ws[i * 64 + o0];
    float a0 = as_[i * 32 + bq];
    float a1 = as_[i * 32 + bq + 16];
#pragma unroll
    for (int q = 0; q < 4; ++q) {
      acc0[q] += a0 * wv[q];
      acc1[q] += a1 * wv[q];
    }
  }

#pragma unroll
  for (int q = 0; q < 4; ++q) {
    outp[(size_t)(bq * 64 + o0 + q) * 518 + p] = acc0[q];
    outp[(size_t)((bq + 16) * 64 + o0 + q) * 518 + p] = acc1[q];
  }
}

// ---------------- Fused epilogue: synthesis cascade 4->3->2 (windowed, in-LDS)
// + level-1 IDWT + MFMA dense shortcut + bias + mish -> fp32.
// Windows per n-tile [n0,n0+64): ras 35 <- r2s 21 <- r3s 14 <- a4m/d4m 10.
// All forward windows (no reflection); bounds exact at bx=0 and bx=127.
#define RAS 68
__global__ __launch_bounds__(256) void k_epilogue(const float* __restrict__ a4m,
                                                  const float* __restrict__ d4m,
                                                  const float* __restrict__ d3,
                                                  const __hip_bfloat16* __restrict__ d2,
                                                  const __hip_bfloat16* __restrict__ dd1,
                                                  const float* __restrict__ x,
                                                  const float* __restrict__ dk,
                                                  const float* __restrict__ bias,
                                                  float* __restrict__ out) {
  const int b = blockIdx.y;
  const int bx = blockIdx.x;
  const int n0 = bx * 64;
  const int u0 = n0 >> 1;
  const int tid = threadIdx.x;
  const int lane = tid & 63;
  const int w = tid >> 6;

  __shared__ __hip_bfloat16 Ktf[4096];  // fragment-ordered K^T
  __shared__ float rds[36 * RAS];       // d1 window (35 x 64)
  __shared__ float ras[36 * RAS];       // r1 window (35 x 64), computed in-block
  __shared__ float scr[6045];
  float* sa4 = scr;          // 10 x 65
  float* sd4 = scr + 650;    // 10 x 65
  float* sd3 = scr + 1300;   // 14 x 65
  float* sd2 = scr + 2210;   // 24 x 65 (21 used)
  float* r3s = scr + 3770;   // 14 x 65
  float* r2s = scr + 4680;   // 21 x 65

  // ---- stage Ktf (all threads) ----
  {
    int o = tid & 63;
    int ot = o >> 4, m16o = o & 15;
    for (int it = 0; it < 2; ++it) {
      int slot = (tid >> 6) + 4 * it;
      int ks = slot >> 2, hi = slot & 3;
      int c0 = ks * 32 + hi * 8;
      short8 f;
#pragma unroll
      for (int kq2 = 0; kq2 < 8; ++kq2)
        f[kq2] = f2bs(dk[(size_t)(c0 + kq2) * 64 + o]);
      *(short8*)&Ktf[((ot * 2 + ks) * 64 + hi * 16 + m16o) * 8] = f;
    }
  }
  // ---- stage cascade windows (4 parts x 64 channels) ----
  {
    const int o = tid & 63;
    const int part = tid >> 6;
    const size_t r = (size_t)b * 64 + o;
    if (part == 0) {
      // a4m/d4m rows are 2072B (8-aligned only) -> float2 loads
      const float2* pa = (const float2*)(a4m + r * 518 + bx * 4);
      const float2* pd = (const float2*)(d4m + r * 518 + bx * 4);
#pragma unroll
      for (int q = 0; q < 5; ++q) {
        float2 va = pa[q], vd = pd[q];
        sa4[(2 * q + 0) * 65 + o] = va.x; sa4[(2 * q + 1) * 65 + o] = va.y;
        sd4[(2 * q + 0) * 65 + o] = vd.x; sd4[(2 * q + 1) * 65 + o] = vd.y;
      }
    } else if (part == 1) {
      const float2* p3 = (const float2*)(d3 + r * 1030 + bx * 8);
#pragma unroll
      for (int q = 0; q < 7; ++q) {
        float2 v = p3[q];
        sd3[(2 * q + 0) * 65 + o] = v.x; sd3[(2 * q + 1) * 65 + o] = v.y;
      }
    } else if (part == 2) {
      const ushort4* p24 = (const ushort4*)(d2 + r * S2R + bx * 16);
#pragma unroll
      for (int q = 0; q < 6; ++q) {
        ushort4 v = p24[q];
        sd2[(4 * q + 0) * 65 + o] = bfu(v.x); sd2[(4 * q + 1) * 65 + o] = bfu(v.y);
        sd2[(4 * q + 2) * 65 + o] = bfu(v.z); sd2[(4 * q + 3) * 65 + o] = bfu(v.w);
      }
    } else {
      const ushort4* pd1 = (const ushort4*)(dd1 + r * S1R + u0);
#pragma unroll
      for (int q = 0; q < 9; ++q) {
        ushort4 v = pd1[q];
        int i0 = 4 * q;
        rds[(i0 + 0) * RAS + o] = bfu(v.x); rds[(i0 + 1) * RAS + o] = bfu(v.y);
        rds[(i0 + 2) * RAS + o] = bfu(v.z); rds[(i0 + 3) * RAS + o] = bfu(v.w);
      }
    }
  }
  __syncthreads();

  // ---- cascade: level 4 -> r3 window (14) ----
  for (int it = tid; it < 14 * 64; it += 256) {
    int o = it & 63, wc = it >> 6;
    int base = wc >> 1, par = wc & 1;
    float acc = 0.f;
#pragma unroll
    for (int t = 0; t < 4; ++t) {
      int i = base + 3 - t;
      float fl = par ? c_RL[2 * t + 1] : c_RL[2 * t];
      float fh = par ? c_RH[2 * t + 1] : c_RH[2 * t];
      acc += fl * sa4[i * 65 + o] + fh * sd4[i * 65 + o];
    }
    r3s[wc * 65 + o] = acc;
  }
  __syncthreads();
  // ---- level 3 -> r2 window (21) ----
  for (int it = tid; it < 21 * 64; it += 256) {
    int o = it & 63, vc = it >> 6;
    int base = vc >> 1, par = vc & 1;
    float acc = 0.f;
#pragma unroll
    for (int t = 0; t < 4; ++t) {
      int i = base + 3 - t;
      float fl = par ? c_RL[2 * t + 1] : c_RL[2 * t];
      float fh = par ? c_RH[2 * t + 1] : c_RH[2 * t];
      acc += fl * r3s[i * 65 + o] + fh * sd3[i * 65 + o];
    }
    r2s[vc * 65 + o] = acc;
  }
  __syncthreads();
  // ---- level 2 -> r1 window (35) ----
  for (int it = tid; it < 35 * 64; it += 256) {
    int o = it & 63, uc = it >> 6;
    int base = uc >> 1, par = uc & 1;
    float acc = 0.f;
#pragma unroll
    for (int t = 0; t < 4; ++t) {
      int i = base + 3 - t;
      float fl = par ? c_RL[2 * t + 1] : c_RL[2 * t];
      float fh = par ? c_RH[2 * t + 1] : c_RH[2 * t];
      acc += fl * r2s[i * 65 + o] + fh * sd2[i * 65 + o];
    }
    ras[uc * RAS + o] = acc;
  }
  __syncthreads();

  // ---- MFMA dense shortcut ----
  const int m16 = lane & 15;
  const int kq = (lane >> 4) * 8;
  const int nrow = w * 16 + m16;
  const float* xrow = x + ((size_t)b * 8192 + n0 + nrow) * 64;

  floatx4 acc[4];
#pragma unroll
  for (int ot = 0; ot < 4; ++ot) acc[ot] = (floatx4){0.f, 0.f, 0.f, 0.f};

#pragma unroll
  for (int ks = 0; ks < 2; ++ks) {
    float4 xa = *(const float4*)(xrow + ks * 32 + kq);
    float4 xb = *(const float4*)(xrow + ks * 32 + kq + 4);
    short8 af;
    af[0] = f2bs(xa.x); af[1] = f2bs(xa.y); af[2] = f2bs(xa.z); af[3] = f2bs(xa.w);
    af[4] = f2bs(xb.x); af[5] = f2bs(xb.y); af[6] = f2bs(xb.z); af[7] = f2bs(xb.w);
#pragma unroll
    for (int ot = 0; ot < 4; ++ot) {
      short8 bf = *(const short8*)&Ktf[((ot * 2 + ks) * 64 + lane) * 8];
      acc[ot] = __builtin_amdgcn_mfma_f32_16x16x32_bf16(af, bf, acc[ot], 0, 0, 0);
    }
  }

  // ---- final IDWT + bias + mish ----
  const int rbase = (lane >> 4) * 4;
#pragma unroll
  for (int ot = 0; ot < 4; ++ot) {
    int o_loc = ot * 16 + m16;
    float bo = bias[o_loc];
#pragma unroll
    for (int rg = 0; rg < 4; ++rg) {
      int n_loc = w * 16 + rbase + rg;
      int ul = n_loc >> 1, par = n_loc & 1;
      float wv = 0.f;
#pragma unroll
      for (int t = 0; t < 4; ++t) {
        int i = ul + 3 - t;
        float fl = par ? c_RL[2 * t + 1] : c_RL[2 * t];
        float fh = par ? c_RH[2 * t + 1] : c_RH[2 * t];
        wv += fl * ras[i * RAS + o_loc] + fh * rds[i * RAS + o_loc];
      }
      float v = acc[ot][rg] + wv + bo;
      float e = __expf(fminf(v, 15.f));
      float num = e * (e + 2.f);
      float mm = (v > 15.f) ? v : v * (num / (num + 2.f));
      __builtin_nontemporal_store(mm, &out[((size_t)b * 8192 + n0 + n_loc) * 64 + o_loc]);
    }
  }
}

// ---------------- host ----------------
extern "C" void kernel_launch(void* const* d_in, const int* in_sizes, int n_in,
                              void* d_out, int out_size, void* d_ws, size_t ws_size,
                              hipStream_t stream) {
  const float* x    = (const float*)d_in[0];
  const float* w1   = (const float*)d_in[1];
  const float* w2   = (const float*)d_in[2];
  const float* dk   = (const float*)d_in[3];
  const float* bias = (const float*)d_in[4];
  float* out = (float*)d_out;

  const size_t R = 2048;

  float* wf = (float*)d_ws;
  float* d3f = wf; wf += R * 1030;
  float* a4t = wf; wf += R * 518;   // transposed: [p][i*32+b]
  float* d4t = wf; wf += R * 518;
  float* a4m = wf; wf += R * 518;   // mix outputs, row-major (b*64+o)
  float* d4m = wf; wf += R * 518;
  float* wt1 = wf; wf += (size_t)518 * 4096;  // transposed weights [p][i*64+o]
  float* wt2 = wf; wf += (size_t)518 * 4096;
  __hip_bfloat16* wb = (__hip_bfloat16*)wf;
  __hip_bfloat16* a1b = wb; wb += R * S1R;  // analysis a1
  __hip_bfloat16* d1b = wb; wb += R * S1R;
  __hip_bfloat16* d2b = wb; wb += R * S2R;

  k_wT<<<dim3(64, 9, 2), 256, 0, stream>>>(w1, w2, wt1, wt2);
  k_dwt_first<<<dim3(65, 32), 256, 0, stream>>>(x, a1b, d1b);
  k_ana234<<<dim3(2048), 256, 0, stream>>>(a1b, d2b, d3f, a4t, d4t);
  k_mix_pc<<<dim3(518, 2), 256, 0, stream>>>(wt1, wt2, a4t, d4t, a4m, d4m);
  k_epilogue<<<dim3(128, 32), 256, 0, stream>>>(a4m, d4m, d3f, d2b, d1b, x, dk, bias, out);
}

// Round 8
// 266.796 us; speedup vs baseline: 1.0029x; 1.0029x over previous
//
#include <hip/hip_runtime.h>
#include <hip/hip_bf16.h>
#include <stdint.h>

typedef __attribute__((ext_vector_type(8))) short short8;
typedef __attribute__((ext_vector_type(4))) float floatx4;

// ---------------- db4 filter constants ----------------
__device__ __constant__ float c_DL[8] = {
    -0.010597401784997278f, 0.032883011666982945f, 0.030841381835986965f,
    -0.18703481171888114f, -0.02798376941698385f, 0.6308807679295904f,
    0.7148465705525415f, 0.23037781330885523f};
__device__ __constant__ float c_DH[8] = {
    -0.23037781330885523f, 0.7148465705525415f, -0.6308807679295904f,
    -0.02798376941698385f, 0.18703481171888114f, 0.030841381835986965f,
    -0.032883011666982945f, -0.010597401784997278f};
__device__ __constant__ float c_RL[8] = {
    0.23037781330885523f, 0.7148465705525415f, 0.6308807679295904f,
    -0.02798376941698385f, -0.18703481171888114f, 0.030841381835986965f,
    0.032883011666982945f, -0.010597401784997278f};
__device__ __constant__ float c_RH[8] = {
    -0.010597401784997278f, -0.032883011666982945f, 0.030841381835986965f,
    0.18703481171888114f, -0.02798376941698385f, -0.6308807679295904f,
    0.7148465705525415f, -0.23037781330885523f};

__device__ __forceinline__ float bflo(uint32_t u) { return __uint_as_float(u << 16); }
__device__ __forceinline__ float bfhi(uint32_t u) { return __uint_as_float(u & 0xffff0000u); }
__device__ __forceinline__ float bfu(unsigned short u) { return __uint_as_float(((uint32_t)u) << 16); }
__device__ __forceinline__ float ldf(const float* p, size_t i) { return p[i]; }
__device__ __forceinline__ float ldf(const __hip_bfloat16* p, size_t i) { return __bfloat162float(p[i]); }
__device__ __forceinline__ void stf(float* p, size_t i, float v) { p[i] = v; }
__device__ __forceinline__ void stf(__hip_bfloat16* p, size_t i, float v) { p[i] = __float2bfloat16(v); }
__device__ __forceinline__ short f2bs(float f) {
  __hip_bfloat16 h = __float2bfloat16(f);
  return *reinterpret_cast<short*>(&h);
}

__device__ __forceinline__ int reflect_idx(int t, int n) {
  if (t < 0) t = -1 - t;
  if (t >= n) t = 2 * n - 1 - t;
  return t;
}

#define S1R 4100
#define S2R 2056

// ---------------- Weight transpose: w[i][o][p] -> wt[p][i*64+o]
__global__ __launch_bounds__(256) void k_wT(const float* __restrict__ w1,
                                            const float* __restrict__ w2,
                                            float* __restrict__ wt1,
                                            float* __restrict__ wt2) {
  const float* w = blockIdx.z ? w2 : w1;
  float* wt = blockIdx.z ? wt2 : wt1;
  const int io0 = blockIdx.x * 64;
  const int p0 = blockIdx.y * 64;
  const int pw = min(64, 518 - p0);
  const int tid = threadIdx.x;
  __shared__ float ts[64 * 65];
  for (int idx = tid; idx < 64 * 64; idx += 256) {
    int row = idx >> 6, col = idx & 63;
    if (col < pw) ts[row * 65 + col] = w[(size_t)(io0 + row) * 518 + p0 + col];
  }
  __syncthreads();
  for (int idx = tid; idx < 64 * 64; idx += 256) {
    int pl = idx >> 6, io = idx & 63;
    if (pl < pw) wt[(size_t)(p0 + pl) * 4096 + io0 + io] = ts[io * 65 + pl];
  }
}

// ---------------- Level-1 DWT: x (B,N,C) fp32 -> a1 row-major bf16, d1t[k][r] bf16.
// d1 written k-major via in-LDS transpose: block covers 64k x 64c at fixed b ->
// each 128B line of d1t fully written in-block (same XCD, full-line merge).
#define NT1 134
#define XTS 138
__global__ __launch_bounds__(256) void k_dwt_first(const float* __restrict__ x,
                                                   __hip_bfloat16* __restrict__ outa,
                                                   __hip_bfloat16* __restrict__ outdt) {
  const int b = blockIdx.y;
  const int k0 = blockIdx.x * 64;
  const int tid = threadIdx.x;
  __shared__ float xs[64 * XTS];              // xs[c][nrow]
  __shared__ __hip_bfloat16 lds_d[64 * 65];   // d-tile [k_loc][c]

  const float4* x4 = (const float4*)x;
  for (int idx = tid; idx < NT1 * 16; idx += 256) {
    int nl = idx >> 4, cq = idx & 15;
    int t = 2 * k0 - 6 + nl;
    int n = reflect_idx(t, 8192);
    float4 v = x4[((size_t)b * 8192 + n) * 16 + cq];
    xs[(4 * cq + 0) * XTS + nl] = v.x;
    xs[(4 * cq + 1) * XTS + nl] = v.y;
    xs[(4 * cq + 2) * XTS + nl] = v.z;
    xs[(4 * cq + 3) * XTS + nl] = v.w;
  }
  __syncthreads();

  const int kk = tid & 63;
  const int k = k0 + kk;
  const bool act = (k < 4099);
  for (int c = (tid >> 6); c < 64; c += 4) {
    if (act) {
      const float2* p = (const float2*)&xs[c * XTS + 2 * kk];
      float2 p0 = p[0], p1 = p[1], p2 = p[2], p3 = p[3];
      float lo = c_DL[0] * p3.y + c_DL[1] * p3.x + c_DL[2] * p2.y + c_DL[3] * p2.x +
                 c_DL[4] * p1.y + c_DL[5] * p1.x + c_DL[6] * p0.y + c_DL[7] * p0.x;
      float hi = c_DH[0] * p3.y + c_DH[1] * p3.x + c_DH[2] * p2.y + c_DH[3] * p2.x +
                 c_DH[4] * p1.y + c_DH[5] * p1.x + c_DH[6] * p0.y + c_DH[7] * p0.x;
      outa[((size_t)b * 64 + c) * S1R + k] = __float2bfloat16(lo);
      lds_d[kk * 65 + c] = __float2bfloat16(hi);
    }
  }
  __syncthreads();
  for (int idx = tid; idx < 4096; idx += 256) {
    int k_loc = idx >> 6, c = idx & 63;
    if (k0 + k_loc < 4099)
      outdt[(size_t)(k0 + k_loc) * 2048 + b * 64 + c] = lds_d[k_loc * 65 + c];
  }
}

// ---------------- Fused analysis levels 2..4, one row per block (as R6)
__global__ __launch_bounds__(256) void k_ana234(const __hip_bfloat16* __restrict__ a1,
                                                __hip_bfloat16* __restrict__ d2o,
                                                float* __restrict__ d3o,
                                                float* __restrict__ a4o,
                                                float* __restrict__ d4o) {
  const int bid = blockIdx.x;
  const int s = (bid & 7) * 256 + (bid >> 3);  // bijective, XCD-contiguous s-range
  const int i_ch = s >> 5;
  const int bb = s & 31;
  const int r = bb * 64 + i_ch;
  const int tid = threadIdx.x;
  __shared__ float s1[4100];
  __shared__ float s2[2054];
  __shared__ float s3[1032];

  const uint2* row2 = (const uint2*)(a1 + (size_t)r * S1R);
  for (int i = tid; i < 1025; i += 256) {
    uint2 u = row2[i];
    int e = 4 * i;
    s1[e] = bflo(u.x); s1[e + 1] = bfhi(u.x);
    s1[e + 2] = bflo(u.y); s1[e + 3] = bfhi(u.y);
  }
  __syncthreads();

  for (int k = tid; k < 2053; k += 256) {
    float lo = 0.f, hi = 0.f;
    if (k >= 3 && k <= 2048) {
      const float2* p = (const float2*)&s1[2 * k - 6];
      float2 v0 = p[0], v1 = p[1], v2 = p[2], v3 = p[3];
      lo = c_RL[0]*v0.x + c_RL[1]*v0.y + c_RL[2]*v1.x + c_RL[3]*v1.y +
           c_RL[4]*v2.x + c_RL[5]*v2.y + c_RL[6]*v3.x + c_RL[7]*v3.y;
      hi = c_RH[0]*v0.x + c_RH[1]*v0.y + c_RH[2]*v1.x + c_RH[3]*v1.y +
           c_RH[4]*v2.x + c_RH[5]*v2.y + c_RH[6]*v3.x + c_RH[7]*v3.y;
    } else {
#pragma unroll
      for (int j = 0; j < 8; ++j) {
        float v = s1[reflect_idx(2 * k + 1 - j, 4099)];
        lo += c_DL[j] * v; hi += c_DH[j] * v;
      }
    }
    d2o[(size_t)r * S2R + k] = __float2bfloat16(hi);
    s2[k] = lo;
  }
  __syncthreads();

  for (int k = tid; k < 1030; k += 256) {
    float lo = 0.f, hi = 0.f;
    if (k >= 3 && k <= 1025) {
      const float2* p = (const float2*)&s2[2 * k - 6];
      float2 v0 = p[0], v1 = p[1], v2 = p[2], v3 = p[3];
      lo = c_RL[0]*v0.x + c_RL[1]*v0.y + c_RL[2]*v1.x + c_RL[3]*v1.y +
           c_RL[4]*v2.x + c_RL[5]*v2.y + c_RL[6]*v3.x + c_RL[7]*v3.y;
      hi = c_RH[0]*v0.x + c_RH[1]*v0.y + c_RH[2]*v1.x + c_RH[3]*v1.y +
           c_RH[4]*v2.x + c_RH[5]*v2.y + c_RH[6]*v3.x + c_RH[7]*v3.y;
    } else {
#pragma unroll
      for (int j = 0; j < 8; ++j) {
        float v = s2[reflect_idx(2 * k + 1 - j, 2053)];
        lo += c_DL[j] * v; hi += c_DH[j] * v;
      }
    }
    d3o[(size_t)r * 1030 + k] = hi;
    s3[k] = lo;
  }
  __syncthreads();

  for (int k = tid; k < 518; k += 256) {
    float lo = 0.f, hi = 0.f;
    if (k >= 3 && k <= 514) {
      const float2* p = (const float2*)&s3[2 * k - 6];
      float2 v0 = p[0], v1 = p[1], v2 = p[2], v3 = p[3];
      lo = c_RL[0]*v0.x + c_RL[1]*v0.y + c_RL[2]*v1.x + c_RL[3]*v1.y +
           c_RL[4]*v2.x + c_RL[5]*v2.y + c_RL[6]*v3.x + c_RL[7]*v3.y;
      hi = c_RH[0]*v0.x + c_RH[1]*v0.y + c_RH[2]*v1.x + c_RH[3]*v1.y +
           c_RH[4]*v2.x + c_RH[5]*v2.y + c_RH[6]*v3.x + c_RH[7]*v3.y;
    } else {
#pragma unroll
      for (int j = 0; j < 8; ++j) {
        float v = s3[reflect_idx(2 * k + 1 - j, 1030)];
        lo += c_DL[j] * v; hi += c_DH[j] * v;
      }
    }
    a4o[(size_t)k * 2048 + s] = lo;
    d4o[(size_t)k * 2048 + s] = hi;
  }
}

// ---------------- Tiled transpose: src[r][*] (row stride srcStride) -> dst[k][2048]
template <typename T>
__global__ __launch_bounds__(256) void k_t23(const T* __restrict__ src, T* __restrict__ dst,
                                             int srcStride, int nk) {
  const int k0 = blockIdx.x * 64;
  const int r0 = blockIdx.y * 64;
  const int tid = threadIdx.x;
  __shared__ float ts[64 * 65];
  for (int idx = tid; idx < 4096; idx += 256) {
    int rl = idx >> 6, kl = idx & 63;
    if (k0 + kl < nk) ts[rl * 65 + kl] = ldf(src, (size_t)(r0 + rl) * srcStride + k0 + kl);
  }
  __syncthreads();
  for (int idx = tid; idx < 4096; idx += 256) {
    int kl = idx >> 6, rl = idx & 63;
    if (k0 + kl < nk) stf(dst, (size_t)(k0 + kl) * 2048 + r0 + rl, ts[rl * 65 + kl]);
  }
}

// ---------------- Channel mixing: one block per (p, a-or-d); staging contiguous,
// output TRANSPOSED am_t[p][r] (contiguous writes; epilogue reads coalesced).
__global__ __launch_bounds__(256) void k_mix_pc(const float* __restrict__ wt1,
                                                const float* __restrict__ wt2,
                                                const float* __restrict__ a4t,
                                                const float* __restrict__ d4t,
                                                float* __restrict__ amt,
                                                float* __restrict__ dmt) {
  const int bx = blockIdx.x;
  const int xcd = bx & 7;
  const int j = bx >> 3;
  const int p = (xcd < 6) ? (xcd * 65 + j) : (390 + (xcd - 6) * 64 + j);

  const float* w = blockIdx.y ? wt2 : wt1;
  const float* act = blockIdx.y ? d4t : a4t;
  float* outp = blockIdx.y ? dmt : amt;

  __shared__ float ws[4096];   // ws[i*64+o]
  __shared__ float as_[2048];  // as_[i*32+b]
  const int tid = threadIdx.x;

  const float4* wg = (const float4*)(w + (size_t)p * 4096);
  const float4* ag = (const float4*)(act + (size_t)p * 2048);
  float4* ws4 = (float4*)ws;
  float4* as4 = (float4*)as_;
  for (int t = tid; t < 1024; t += 256) ws4[t] = wg[t];
  for (int t = tid; t < 512; t += 256) as4[t] = ag[t];
  __syncthreads();

  const int o0 = (tid & 15) * 4;
  const int bq = tid >> 4;
  floatx4 acc0 = {0.f, 0.f, 0.f, 0.f}, acc1 = {0.f, 0.f, 0.f, 0.f};

#pragma unroll 8
  for (int i = 0; i < 64; ++i) {
    floatx4 wv = *(const floatx4*)&ws[i * 64 + o0];
    float a0 = as_[i * 32 + bq];
    float a1 = as_[i * 32 + bq + 16];
#pragma unroll
    for (int q = 0; q < 4; ++q) {
      acc0[q] += a0 * wv[q];
      acc1[q] += a1 * wv[q];
    }
  }

  // transposed, contiguous: amt[p*2048 + b*64 + o]
  *(floatx4*)&outp[(size_t)p * 2048 + bq * 64 + o0] = acc0;
  *(floatx4*)&outp[(size_t)p * 2048 + (bq + 16) * 64 + o0] = acc1;
}

// ---------------- Fused epilogue: windowed synthesis cascade (all inputs k-major,
// every staging load line-coalesced) + MFMA shortcut + bias + mish.
#define RAS 68
__global__ __launch_bounds__(256) void k_epilogue(const float* __restrict__ a4mt,
                                                  const float* __restrict__ d4mt,
                                                  const float* __restrict__ d3t,
                                                  const __hip_bfloat16* __restrict__ d2t,
                                                  const __hip_bfloat16* __restrict__ d1t,
                                                  const float* __restrict__ x,
                                                  const float* __restrict__ dk,
                                                  const float* __restrict__ bias,
                                                  float* __restrict__ out) {
  const int b = blockIdx.y;
  const int bx = blockIdx.x;
  const int n0 = bx * 64;
  const int u0 = n0 >> 1;
  const int tid = threadIdx.x;
  const int lane = tid & 63;
  const int w = tid >> 6;

  __shared__ __hip_bfloat16 Ktf[4096];  // fragment-ordered K^T
  __shared__ float rds[36 * RAS];       // d1 window (35 x 64)
  __shared__ float ras[36 * RAS];       // r1 window (35 x 64), computed in-block
  __shared__ float scr[6045];
  float* sa4 = scr;          // 10 x 65
  float* sd4 = scr + 650;    // 10 x 65
  float* sd3 = scr + 1300;   // 14 x 65
  float* sd2 = scr + 2210;   // 24 x 65 (21 used)
  float* r3s = scr + 3770;   // 14 x 65
  float* r2s = scr + 4680;   // 21 x 65

  // ---- stage Ktf (all threads) ----
  {
    int o = tid & 63;
    int ot = o >> 4, m16o = o & 15;
    for (int it = 0; it < 2; ++it) {
      int slot = (tid >> 6) + 4 * it;
      int ks = slot >> 2, hi = slot & 3;
      int c0 = ks * 32 + hi * 8;
      short8 f;
#pragma unroll
      for (int kq2 = 0; kq2 < 8; ++kq2)
        f[kq2] = f2bs(dk[(size_t)(c0 + kq2) * 64 + o]);
      *(short8*)&Ktf[((ot * 2 + ks) * 64 + hi * 16 + m16o) * 8] = f;
    }
  }
  // ---- stage cascade windows: ALL line-coalesced (one 128-256B row per load) ----
  {
    const int o = lane;
    const int rbase = b * 64 + o;
    if (w == 0) {
#pragma unroll
      for (int j2 = 0; j2 < 10; ++j2) {
        sa4[j2 * 65 + o] = a4mt[(size_t)(bx * 4 + j2) * 2048 + rbase];
        sd4[j2 * 65 + o] = d4mt[(size_t)(bx * 4 + j2) * 2048 + rbase];
      }
    } else if (w == 1) {
#pragma unroll
      for (int j2 = 0; j2 < 14; ++j2)
        sd3[j2 * 65 + o] = d3t[(size_t)(bx * 8 + j2) * 2048 + rbase];
#pragma unroll
      for (int j2 = 25; j2 < 35; ++j2)
        rds[j2 * RAS + o] = __bfloat162float(d1t[(size_t)(u0 + j2) * 2048 + rbase]);
    } else if (w == 2) {
#pragma unroll
      for (int j2 = 0; j2 < 21; ++j2)
        sd2[j2 * 65 + o] = __bfloat162float(d2t[(size_t)(bx * 16 + j2) * 2048 + rbase]);
    } else {
#pragma unroll
      for (int j2 = 0; j2 < 25; ++j2)
        rds[j2 * RAS + o] = __bfloat162float(d1t[(size_t)(u0 + j2) * 2048 + rbase]);
    }
  }
  __syncthreads();

  // ---- cascade: level 4 -> r3 window (14) ----
  for (int it = tid; it < 14 * 64; it += 256) {
    int o = it & 63, wc = it >> 6;
    int base = wc >> 1, par = wc & 1;
    float acc = 0.f;
#pragma unroll
    for (int t = 0; t < 4; ++t) {
      int i = base + 3 - t;
      float fl = par ? c_RL[2 * t + 1] : c_RL[2 * t];
      float fh = par ? c_RH[2 * t + 1] : c_RH[2 * t];
      acc += fl * sa4[i * 65 + o] + fh * sd4[i * 65 + o];
    }
    r3s[wc * 65 + o] = acc;
  }
  __syncthreads();
  // ---- level 3 -> r2 window (21) ----
  for (int it = tid; it < 21 * 64; it += 256) {
    int o = it & 63, vc = it >> 6;
    int base = vc >> 1, par = vc & 1;
    float acc = 0.f;
#pragma unroll
    for (int t = 0; t < 4; ++t) {
      int i = base + 3 - t;
      float fl = par ? c_RL[2 * t + 1] : c_RL[2 * t];
      float fh = par ? c_RH[2 * t + 1] : c_RH[2 * t];
      acc += fl * r3s[i * 65 + o] + fh * sd3[i * 65 + o];
    }
    r2s[vc * 65 + o] = acc;
  }
  __syncthreads();
  // ---- level 2 -> r1 window (35) ----
  for (int it = tid; it < 35 * 64; it += 256) {
    int o = it & 63, uc = it >> 6;
    int base = uc >> 1, par = uc & 1;
    float acc = 0.f;
#pragma unroll
    for (int t = 0; t < 4; ++t) {
      int i = base + 3 - t;
      float fl = par ? c_RL[2 * t + 1] : c_RL[2 * t];
      float fh = par ? c_RH[2 * t + 1] : c_RH[2 * t];
      acc += fl * r2s[i * 65 + o] + fh * sd2[i * 65 + o];
    }
    ras[uc * RAS + o] = acc;
  }
  __syncthreads();

  // ---- MFMA dense shortcut ----
  const int m16 = lane & 15;
  const int kq = (lane >> 4) * 8;
  const int nrow = w * 16 + m16;
  const float* xrow = x + ((size_t)b * 8192 + n0 + nrow) * 64;

  floatx4 acc[4];
#pragma unroll
  for (int ot = 0; ot < 4; ++ot) acc[ot] = (floatx4){0.f, 0.f, 0.f, 0.f};

#pragma unroll
  for (int ks = 0; ks < 2; ++ks) {
    float4 xa = *(const float4*)(xrow + ks * 32 + kq);
    float4 xb = *(const float4*)(xrow + ks * 32 + kq + 4);
    short8 af;
    af[0] = f2bs(xa.x); af[1] = f2bs(xa.y); af[2] = f2bs(xa.z); af[3] = f2bs(xa.w);
    af[4] = f2bs(xb.x); af[5] = f2bs(xb.y); af[6] = f2bs(xb.z); af[7] = f2bs(xb.w);
#pragma unroll
    for (int ot = 0; ot < 4; ++ot) {
      short8 bf = *(const short8*)&Ktf[((ot * 2 + ks) * 64 + lane) * 8];
      acc[ot] = __builtin_amdgcn_mfma_f32_16x16x32_bf16(af, bf, acc[ot], 0, 0, 0);
    }
  }

  // ---- final IDWT + bias + mish ----
  const int rbase2 = (lane >> 4) * 4;
#pragma unroll
  for (int ot = 0; ot < 4; ++ot) {
    int o_loc = ot * 16 + m16;
    float bo = bias[o_loc];
#pragma unroll
    for (int rg = 0; rg < 4; ++rg) {
      int n_loc = w * 16 + rbase2 + rg;
      int ul = n_loc >> 1, par = n_loc & 1;
      float wv = 0.f;
#pragma unroll
      for (int t = 0; t < 4; ++t) {
        int i = ul + 3 - t;
        float fl = par ? c_RL[2 * t + 1] : c_RL[2 * t];
        float fh = par ? c_RH[2 * t + 1] : c_RH[2 * t];
        wv += fl * ras[i * RAS + o_loc] + fh * rds[i * RAS + o_loc];
      }
      float v = acc[ot][rg] + wv + bo;
      float e = __expf(fminf(v, 15.f));
      float num = e * (e + 2.f);
      float mm = (v > 15.f) ? v : v * (num / (num + 2.f));
      __builtin_nontemporal_store(mm, &out[((size_t)b * 8192 + n0 + n_loc) * 64 + o_loc]);
    }
  }
}

// ---------------- host ----------------
extern "C" void kernel_launch(void* const* d_in, const int* in_sizes, int n_in,
                              void* d_out, int out_size, void* d_ws, size_t ws_size,
                              hipStream_t stream) {
  const float* x    = (const float*)d_in[0];
  const float* w1   = (const float*)d_in[1];
  const float* w2   = (const float*)d_in[2];
  const float* dk   = (const float*)d_in[3];
  const float* bias = (const float*)d_in[4];
  float* out = (float*)d_out;

  const size_t R = 2048;

  float* wf = (float*)d_ws;
  float* d3f  = wf; wf += R * 1030;               // d3 row-major
  float* d3t  = wf; wf += R * 1030;               // d3 transposed [k][r]
  float* a4t  = wf; wf += R * 518;                // [p][i*32+b] (s-order, for mix)
  float* d4t  = wf; wf += R * 518;
  float* a4mt = wf; wf += R * 518;                // mix out transposed [p][r]
  float* d4mt = wf; wf += R * 518;
  float* wt1  = wf; wf += (size_t)518 * 4096;
  float* wt2  = wf; wf += (size_t)518 * 4096;
  __hip_bfloat16* wb = (__hip_bfloat16*)wf;
  __hip_bfloat16* a1b = wb; wb += R * S1R;        // a1 row-major (dead after ana234)
  __hip_bfloat16* d1t = wb; wb += R * S1R;        // d1 transposed [k][r]
  __hip_bfloat16* d2b = wb; wb += R * S2R;        // d2 row-major
  __hip_bfloat16* d2t = a1b;                      // alias: a1b dead after k_ana234
  // total ~92.8 MB

  k_wT<<<dim3(64, 9, 2), 256, 0, stream>>>(w1, w2, wt1, wt2);
  k_dwt_first<<<dim3(65, 32), 256, 0, stream>>>(x, a1b, d1t);
  k_ana234<<<dim3(2048), 256, 0, stream>>>(a1b, d2b, d3f, a4t, d4t);
  k_mix_pc<<<dim3(518, 2), 256, 0, stream>>>(wt1, wt2, a4t, d4t, a4mt, d4mt);
  k_t23<__hip_bfloat16><<<dim3(33, 32), 256, 0, stream>>>(d2b, d2t, S2R, 2053);
  k_t23<float><<<dim3(17, 32), 256, 0, stream>>>(d3f, d3t, 1030, 1030);
  k_epilogue<<<dim3(128, 32), 256, 0, stream>>>(a4mt, d4mt, d3t, d2t, d1t, x, dk, bias, out);
}

// Round 10
// 249.005 us; speedup vs baseline: 1.0746x; 1.0714x over previous
//
#include <hip/hip_runtime.h>
#include <hip/hip_bf16.h>
#include <stdint.h>

typedef __attribute__((ext_vector_type(8))) short short8;
typedef __attribute__((ext_vector_type(4))) float floatx4;

// ---------------- db4 filter constants ----------------
__device__ __constant__ float c_DL[8] = {
    -0.010597401784997278f, 0.032883011666982945f, 0.030841381835986965f,
    -0.18703481171888114f, -0.02798376941698385f, 0.6308807679295904f,
    0.7148465705525415f, 0.23037781330885523f};
__device__ __constant__ float c_DH[8] = {
    -0.23037781330885523f, 0.7148465705525415f, -0.6308807679295904f,
    -0.02798376941698385f, 0.18703481171888114f, 0.030841381835986965f,
    -0.032883011666982945f, -0.010597401784997278f};
__device__ __constant__ float c_RL[8] = {
    0.23037781330885523f, 0.7148465705525415f, 0.6308807679295904f,
    -0.02798376941698385f, -0.18703481171888114f, 0.030841381835986965f,
    0.032883011666982945f, -0.010597401784997278f};
__device__ __constant__ float c_RH[8] = {
    -0.010597401784997278f, -0.032883011666982945f, 0.030841381835986965f,
    0.18703481171888114f, -0.02798376941698385f, -0.6308807679295904f,
    0.7148465705525415f, -0.23037781330885523f};

__device__ __forceinline__ float bflo(uint32_t u) { return __uint_as_float(u << 16); }
__device__ __forceinline__ float bfhi(uint32_t u) { return __uint_as_float(u & 0xffff0000u); }
__device__ __forceinline__ float bfu(unsigned short u) { return __uint_as_float(((uint32_t)u) << 16); }
__device__ __forceinline__ short f2bs(float f) {
  __hip_bfloat16 h = __float2bfloat16(f);
  return *reinterpret_cast<short*>(&h);
}

__device__ __forceinline__ int reflect_idx(int t, int n) {
  if (t < 0) t = -1 - t;
  if (t >= n) t = 2 * n - 1 - t;
  return t;
}

// Row strides (padded for aligned vector access)
#define S1R 4100
#define S2R 2056

// ---------------- Weight transpose: w[i][o][p] -> wt[p][i*64+o]
__global__ __launch_bounds__(256) void k_wT(const float* __restrict__ w1,
                                            const float* __restrict__ w2,
                                            float* __restrict__ wt1,
                                            float* __restrict__ wt2) {
  const float* w = blockIdx.z ? w2 : w1;
  float* wt = blockIdx.z ? wt2 : wt1;
  const int io0 = blockIdx.x * 64;
  const int p0 = blockIdx.y * 64;
  const int pw = min(64, 518 - p0);
  const int tid = threadIdx.x;
  __shared__ float ts[64 * 65];
  for (int idx = tid; idx < 64 * 64; idx += 256) {
    int row = idx >> 6, col = idx & 63;
    if (col < pw) ts[row * 65 + col] = w[(size_t)(io0 + row) * 518 + p0 + col];
  }
  __syncthreads();
  for (int idx = tid; idx < 64 * 64; idx += 256) {
    int pl = idx >> 6, io = idx & 63;
    if (pl < pw) wt[(size_t)(p0 + pl) * 4096 + io0 + io] = ts[io * 65 + pl];
  }
}

// ---------------- Level-1 DWT: x (B,N,C) fp32 -> a1,d1 (B*C, stride 4100) bf16
#define NT1 134
#define XTS 138
__global__ __launch_bounds__(256) void k_dwt_first(const float* __restrict__ x,
                                                   __hip_bfloat16* __restrict__ outa,
                                                   __hip_bfloat16* __restrict__ outd) {
  const int b = blockIdx.y;
  const int k0 = blockIdx.x * 64;
  const int tid = threadIdx.x;
  __shared__ float xs[64 * XTS];  // xs[c][nrow]

  const float4* x4 = (const float4*)x;
  for (int idx = tid; idx < NT1 * 16; idx += 256) {
    int nl = idx >> 4, cq = idx & 15;
    int t = 2 * k0 - 6 + nl;
    int n = reflect_idx(t, 8192);
    float4 v = x4[((size_t)b * 8192 + n) * 16 + cq];
    xs[(4 * cq + 0) * XTS + nl] = v.x;
    xs[(4 * cq + 1) * XTS + nl] = v.y;
    xs[(4 * cq + 2) * XTS + nl] = v.z;
    xs[(4 * cq + 3) * XTS + nl] = v.w;
  }
  __syncthreads();

  const int kk = tid & 63;
  const int k = k0 + kk;
  if (k >= 4099) return;
  for (int c = (tid >> 6); c < 64; c += 4) {
    const float2* p = (const float2*)&xs[c * XTS + 2 * kk];
    float2 p0 = p[0], p1 = p[1], p2 = p[2], p3 = p[3];
    float lo = c_DL[0] * p3.y + c_DL[1] * p3.x + c_DL[2] * p2.y + c_DL[3] * p2.x +
               c_DL[4] * p1.y + c_DL[5] * p1.x + c_DL[6] * p0.y + c_DL[7] * p0.x;
    float hi = c_DH[0] * p3.y + c_DH[1] * p3.x + c_DH[2] * p2.y + c_DH[3] * p2.x +
               c_DH[4] * p1.y + c_DH[5] * p1.x + c_DH[6] * p0.y + c_DH[7] * p0.x;
    size_t s = (size_t)b * 64 + c;
    outa[s * S1R + k] = __float2bfloat16(lo);
    outd[s * S1R + k] = __float2bfloat16(hi);
  }
}

// ---------------- Fused analysis levels 2..4, one row per block
// Level-4 outputs written TRANSPOSED: a4t[k*2048 + s], s = i*32 + b.
__global__ __launch_bounds__(256) void k_ana234(const __hip_bfloat16* __restrict__ a1,
                                                __hip_bfloat16* __restrict__ d2o,
                                                float* __restrict__ d3o,
                                                float* __restrict__ a4o,
                                                float* __restrict__ d4o) {
  const int bid = blockIdx.x;
  const int s = (bid & 7) * 256 + (bid >> 3);  // bijective, XCD-contiguous s-range
  const int i_ch = s >> 5;
  const int bb = s & 31;
  const int r = bb * 64 + i_ch;
  const int tid = threadIdx.x;
  __shared__ float s1[4100];
  __shared__ float s2[2054];
  __shared__ float s3[1032];

  const uint2* row2 = (const uint2*)(a1 + (size_t)r * S1R);
  for (int i = tid; i < 1025; i += 256) {
    uint2 u = row2[i];
    int e = 4 * i;
    s1[e] = bflo(u.x); s1[e + 1] = bfhi(u.x);
    s1[e + 2] = bflo(u.y); s1[e + 3] = bfhi(u.y);
  }
  __syncthreads();

  // level 2: n=4099 -> m=2053
  for (int k = tid; k < 2053; k += 256) {
    float lo = 0.f, hi = 0.f;
    if (k >= 3 && k <= 2048) {
      const float2* p = (const float2*)&s1[2 * k - 6];
      float2 v0 = p[0], v1 = p[1], v2 = p[2], v3 = p[3];
      lo = c_RL[0]*v0.x + c_RL[1]*v0.y + c_RL[2]*v1.x + c_RL[3]*v1.y +
           c_RL[4]*v2.x + c_RL[5]*v2.y + c_RL[6]*v3.x + c_RL[7]*v3.y;
      hi = c_RH[0]*v0.x + c_RH[1]*v0.y + c_RH[2]*v1.x + c_RH[3]*v1.y +
           c_RH[4]*v2.x + c_RH[5]*v2.y + c_RH[6]*v3.x + c_RH[7]*v3.y;
    } else {
#pragma unroll
      for (int j = 0; j < 8; ++j) {
        float v = s1[reflect_idx(2 * k + 1 - j, 4099)];
        lo += c_DL[j] * v; hi += c_DH[j] * v;
      }
    }
    d2o[(size_t)r * S2R + k] = __float2bfloat16(hi);
    s2[k] = lo;
  }
  __syncthreads();

  // level 3: n=2053 -> m=1030
  for (int k = tid; k < 1030; k += 256) {
    float lo = 0.f, hi = 0.f;
    if (k >= 3 && k <= 1025) {
      const float2* p = (const float2*)&s2[2 * k - 6];
      float2 v0 = p[0], v1 = p[1], v2 = p[2], v3 = p[3];
      lo = c_RL[0]*v0.x + c_RL[1]*v0.y + c_RL[2]*v1.x + c_RL[3]*v1.y +
           c_RL[4]*v2.x + c_RL[5]*v2.y + c_RL[6]*v3.x + c_RL[7]*v3.y;
      hi = c_RH[0]*v0.x + c_RH[1]*v0.y + c_RH[2]*v1.x + c_RH[3]*v1.y +
           c_RH[4]*v2.x + c_RH[5]*v2.y + c_RH[6]*v3.x + c_RH[7]*v3.y;
    } else {
#pragma unroll
      for (int j = 0; j < 8; ++j) {
        float v = s2[reflect_idx(2 * k + 1 - j, 2053)];
        lo += c_DL[j] * v; hi += c_DH[j] * v;
      }
    }
    d3o[(size_t)r * 1030 + k] = hi;
    s3[k] = lo;
  }
  __syncthreads();

  // level 4: n=1030 -> m=518, transposed scatter (merged in per-XCD L2)
  for (int k = tid; k < 518; k += 256) {
    float lo = 0.f, hi = 0.f;
    if (k >= 3 && k <= 514) {
      const float2* p = (const float2*)&s3[2 * k - 6];
      float2 v0 = p[0], v1 = p[1], v2 = p[2], v3 = p[3];
      lo = c_RL[0]*v0.x + c_RL[1]*v0.y + c_RL[2]*v1.x + c_RL[3]*v1.y +
           c_RL[4]*v2.x + c_RL[5]*v2.y + c_RL[6]*v3.x + c_RL[7]*v3.y;
      hi = c_RH[0]*v0.x + c_RH[1]*v0.y + c_RH[2]*v1.x + c_RH[3]*v1.y +
           c_RH[4]*v2.x + c_RH[5]*v2.y + c_RH[6]*v3.x + c_RH[7]*v3.y;
    } else {
#pragma unroll
      for (int j = 0; j < 8; ++j) {
        float v = s3[reflect_idx(2 * k + 1 - j, 1030)];
        lo += c_DL[j] * v; hi += c_DH[j] * v;
      }
    }
    a4o[(size_t)k * 2048 + s] = lo;
    d4o[(size_t)k * 2048 + s] = hi;
  }
}

// ---------------- Channel mixing: one block per (p, a-or-d), staging contiguous.
__global__ __launch_bounds__(256) void k_mix_pc(const float* __restrict__ wt1,
                                                const float* __restrict__ wt2,
                                                const float* __restrict__ a4t,
                                                const float* __restrict__ d4t,
                                                float* __restrict__ am,
                                                float* __restrict__ dm) {
  const int bx = blockIdx.x;
  const int xcd = bx & 7;
  const int j = bx >> 3;
  const int p = (xcd < 6) ? (xcd * 65 + j) : (390 + (xcd - 6) * 64 + j);

  const float* w = blockIdx.y ? wt2 : wt1;
  const float* act = blockIdx.y ? d4t : a4t;
  float* outp = blockIdx.y ? dm : am;

  __shared__ float ws[4096];   // ws[i*64+o]
  __shared__ float as_[2048];  // as_[i*32+b]
  const int tid = threadIdx.x;

  const float4* wg = (const float4*)(w + (size_t)p * 4096);
  const float4* ag = (const float4*)(act + (size_t)p * 2048);
  float4* ws4 = (float4*)ws;
  float4* as4 = (float4*)as_;
  for (int t = tid; t < 1024; t += 256) ws4[t] = wg[t];
  for (int t = tid; t < 512; t += 256) as4[t] = ag[t];
  __syncthreads();

  const int o0 = (tid & 15) * 4;
  const int bq = tid >> 4;
  floatx4 acc0 = {0.f, 0.f, 0.f, 0.f}, acc1 = {0.f, 0.f, 0.f, 0.f};

#pragma unroll 8
  for (int i = 0; i < 64; ++i) {
    floatx4 wv = *(const floatx4*)&ws[i * 64 + o0];
    float a0 = as_[i * 32 + bq];
    float a1 = as_[i * 32 + bq + 16];
#pragma unroll
    for (int q = 0; q < 4; ++q) {
      acc0[q] += a0 * wv[q];
      acc1[q] += a1 * wv[q];
    }
  }

#pragma unroll
  for (int q = 0; q < 4; ++q) {
    outp[(size_t)(bq * 64 + o0 + q) * 518 + p] = acc0[q];
    outp[(size_t)((bq + 16) * 64 + o0 + q) * 518 + p] = acc1[q];
  }
}

// ---------------- Fused synthesis levels 4->3->2: writes recon1 (bf16) directly.
// d2s kept as raw bf16 bits (ushort) in LDS: identical numerics, 24.7 KB LDS
// (was 28.9) -> 6 blocks/CU.
__global__ __launch_bounds__(256) void k_syn(const float* __restrict__ a4m,
                                             const float* __restrict__ d4m,
                                             const float* __restrict__ d3,
                                             const __hip_bfloat16* __restrict__ d2,
                                             __hip_bfloat16* __restrict__ r1out) {
  const int r = blockIdx.x;
  const int tid = threadIdx.x;
  __shared__ float sa[518], sd[518], s3d[1030], r3[1030], r2[2053];
  __shared__ unsigned short d2s[2056];
  for (int i = tid; i < 518; i += 256) {
    sa[i] = a4m[(size_t)r * 518 + i];
    sd[i] = d4m[(size_t)r * 518 + i];
  }
  for (int i = tid; i < 1030; i += 256) s3d[i] = d3[(size_t)r * 1030 + i];
  {
    const ushort4* p2 = (const ushort4*)(d2 + (size_t)r * S2R);
    for (int i = tid; i < 514; i += 256) {
      ushort4 u = p2[i];
      int e = 4 * i;
      d2s[e] = u.x; d2s[e + 1] = u.y; d2s[e + 2] = u.z; d2s[e + 3] = u.w;
    }
  }
  __syncthreads();
  // level 4 -> r3 (1030)
  for (int s = tid; s < 1030; s += 256) {
    int u = s >> 1, par = s & 1;
    float acc = 0.f;
#pragma unroll
    for (int t = 0; t < 4; ++t) {
      int i = u + 3 - t;
      float fl = par ? c_RL[2 * t + 1] : c_RL[2 * t];
      float fh = par ? c_RH[2 * t + 1] : c_RH[2 * t];
      acc += fl * sa[i] + fh * sd[i];
    }
    r3[s] = acc;
  }
  __syncthreads();
  // level 3 -> r2 (2053), fp32 in LDS
  for (int s = tid; s < 2053; s += 256) {
    int u = s >> 1, par = s & 1;
    float acc = 0.f;
#pragma unroll
    for (int t = 0; t < 4; ++t) {
      int i = u + 3 - t;
      float fl = par ? c_RL[2 * t + 1] : c_RL[2 * t];
      float fh = par ? c_RH[2 * t + 1] : c_RH[2 * t];
      acc += fl * r3[i] + fh * s3d[i];
    }
    r2[s] = acc;
  }
  __syncthreads();
  // level 2 -> r1 (4099), bf16 to global
  for (int s = tid; s < 4099; s += 256) {
    int u = s >> 1, par = s & 1;
    float acc = 0.f;
#pragma unroll
    for (int t = 0; t < 4; ++t) {
      int i = u + 3 - t;
      float fl = par ? c_RL[2 * t + 1] : c_RL[2 * t];
      float fh = par ? c_RH[2 * t + 1] : c_RH[2 * t];
      acc += fl * r2[i] + fh * bfu(d2s[i]);
    }
    r1out[(size_t)r * S1R + s] = __float2bfloat16(acc);
  }
}

// ---------------- Epilogue: MFMA dense shortcut + final IDWT + bias + mish -> fp32
// block 256 (4 waves), tile 64n x 64o, grid (128, 32)
// ra/rd kept as raw bf16 bits (ushort, stride 68): identical numerics,
// LDS 28.2 -> 18.0 KB -> 8 blocks/CU (occupancy was the binding limit at 43%).
#define RAS 68
__global__ __launch_bounds__(256) void k_epilogue(const __hip_bfloat16* __restrict__ r1,
                                                  const __hip_bfloat16* __restrict__ dd1,
                                                  const float* __restrict__ x,
                                                  const float* __restrict__ dk,
                                                  const float* __restrict__ bias,
                                                  float* __restrict__ out) {
  const int b = blockIdx.y;
  const int n0 = blockIdx.x * 64;
  const int u0 = n0 >> 1;
  const int tid = threadIdx.x;
  const int lane = tid & 63;
  const int w = tid >> 6;

  __shared__ __hip_bfloat16 Ktf[4096];    // fragment-ordered K^T
  __shared__ unsigned short ra[36 * RAS];  // r1 window, raw bf16 bits
  __shared__ unsigned short rd[36 * RAS];  // d1 window, raw bf16 bits

  // stage Ktf: thread t owns column o=t&63; (ks,hi) slot = (t>>6)+4*it.
  {
    int o = tid & 63;
    int ot = o >> 4, m16o = o & 15;
    for (int it = 0; it < 2; ++it) {
      int slot = (tid >> 6) + 4 * it;
      int ks = slot >> 2, hi = slot & 3;
      int c0 = ks * 32 + hi * 8;
      short8 f;
#pragma unroll
      for (int kq2 = 0; kq2 < 8; ++kq2)
        f[kq2] = f2bs(dk[(size_t)(c0 + kq2) * 64 + o]);
      *(short8*)&Ktf[((ot * 2 + ks) * 64 + hi * 16 + m16o) * 8] = f;
    }
  }
  // stage ra/rd (35 coeffs x 64 channels), vectorized ushort4 (8B) loads, raw bits.
  {
    int o2 = tid >> 2;
    const ushort4* pr4 = (const ushort4*)(r1 + (size_t)(b * 64 + o2) * S1R + u0);
    const ushort4* pd4 = (const ushort4*)(dd1 + (size_t)(b * 64 + o2) * S1R + u0);
    for (int q = tid & 3; q < 9; q += 4) {
      ushort4 v = pr4[q];
      int i0 = 4 * q;
      ra[(i0 + 0) * RAS + o2] = v.x;
      ra[(i0 + 1) * RAS + o2] = v.y;
      ra[(i0 + 2) * RAS + o2] = v.z;
      ra[(i0 + 3) * RAS + o2] = v.w;
      ushort4 d = pd4[q];
      rd[(i0 + 0) * RAS + o2] = d.x;
      rd[(i0 + 1) * RAS + o2] = d.y;
      rd[(i0 + 2) * RAS + o2] = d.z;
      rd[(i0 + 3) * RAS + o2] = d.w;
    }
  }
  __syncthreads();

  const int m16 = lane & 15;
  const int kq = (lane >> 4) * 8;
  const int nrow = w * 16 + m16;
  const float* xrow = x + ((size_t)b * 8192 + n0 + nrow) * 64;

  floatx4 acc[4];
#pragma unroll
  for (int ot = 0; ot < 4; ++ot) acc[ot] = (floatx4){0.f, 0.f, 0.f, 0.f};

#pragma unroll
  for (int ks = 0; ks < 2; ++ks) {
    float4 xa = *(const float4*)(xrow + ks * 32 + kq);
    float4 xb = *(const float4*)(xrow + ks * 32 + kq + 4);
    short8 af;
    af[0] = f2bs(xa.x); af[1] = f2bs(xa.y); af[2] = f2bs(xa.z); af[3] = f2bs(xa.w);
    af[4] = f2bs(xb.x); af[5] = f2bs(xb.y); af[6] = f2bs(xb.z); af[7] = f2bs(xb.w);
#pragma unroll
    for (int ot = 0; ot < 4; ++ot) {
      short8 bf = *(const short8*)&Ktf[((ot * 2 + ks) * 64 + lane) * 8];
      acc[ot] = __builtin_amdgcn_mfma_f32_16x16x32_bf16(af, bf, acc[ot], 0, 0, 0);
    }
  }

  // epilogue: C/D layout col=lane&15 (o), row=(lane>>4)*4+reg (n)
  const int rbase = (lane >> 4) * 4;
#pragma unroll
  for (int ot = 0; ot < 4; ++ot) {
    int o_loc = ot * 16 + m16;
    float bo = bias[o_loc];
#pragma unroll
    for (int rg = 0; rg < 4; ++rg) {
      int n_loc = w * 16 + rbase + rg;
      int ul = n_loc >> 1, par = n_loc & 1;
      float wv = 0.f;
#pragma unroll
      for (int t = 0; t < 4; ++t) {
        int i = ul + 3 - t;
        float fl = par ? c_RL[2 * t + 1] : c_RL[2 * t];
        float fh = par ? c_RH[2 * t + 1] : c_RH[2 * t];
        wv += fl * bfu(ra[i * RAS + o_loc]) + fh * bfu(rd[i * RAS + o_loc]);
      }
      float v = acc[ot][rg] + wv + bo;
      float e = __expf(fminf(v, 15.f));
      float num = e * (e + 2.f);
      float mm = (v > 15.f) ? v : v * (num / (num + 2.f));
      __builtin_nontemporal_store(mm, &out[((size_t)b * 8192 + n0 + n_loc) * 64 + o_loc]);
    }
  }
}

// ---------------- host ----------------
extern "C" void kernel_launch(void* const* d_in, const int* in_sizes, int n_in,
                              void* d_out, int out_size, void* d_ws, size_t ws_size,
                              hipStream_t stream) {
  const float* x    = (const float*)d_in[0];
  const float* w1   = (const float*)d_in[1];
  const float* w2   = (const float*)d_in[2];
  const float* dk   = (const float*)d_in[3];
  const float* bias = (const float*)d_in[4];
  float* out = (float*)d_out;

  const size_t R = 2048;

  float* wf = (float*)d_ws;
  float* d3f = wf; wf += R * 1030;
  float* a4t = wf; wf += R * 518;   // transposed: [p][i*32+b]
  float* d4t = wf; wf += R * 518;
  float* a4m = wf; wf += R * 518;   // mix outputs, row-major (b*64+o)
  float* d4m = wf; wf += R * 518;
  float* wt1 = wf; wf += (size_t)518 * 4096;  // transposed weights [p][i*64+o]
  float* wt2 = wf; wf += (size_t)518 * 4096;
  __hip_bfloat16* wb = (__hip_bfloat16*)wf;
  __hip_bfloat16* a1b = wb; wb += R * S1R;  // analysis a1, later recon1
  __hip_bfloat16* d1b = wb; wb += R * S1R;
  __hip_bfloat16* d2b = wb; wb += R * S2R;

  k_wT<<<dim3(64, 9, 2), 256, 0, stream>>>(w1, w2, wt1, wt2);
  k_dwt_first<<<dim3(65, 32), 256, 0, stream>>>(x, a1b, d1b);
  k_ana234<<<dim3(2048), 256, 0, stream>>>(a1b, d2b, d3f, a4t, d4t);
  k_mix_pc<<<dim3(518, 2), 256, 0, stream>>>(wt1, wt2, a4t, d4t, a4m, d4m);
  k_syn<<<dim3(2048), 256, 0, stream>>>(a4m, d4m, d3f, d2b, a1b);
  k_epilogue<<<dim3(128, 32), 256, 0, stream>>>(a1b, d1b, x, dk, bias, out);
}

// Round 11
// 246.570 us; speedup vs baseline: 1.0852x; 1.0099x over previous
//
#include <hip/hip_runtime.h>
#include <hip/hip_bf16.h>
#include <stdint.h>

typedef __attribute__((ext_vector_type(8))) short short8;
typedef __attribute__((ext_vector_type(4))) float floatx4;

// ---------------- db4 filter constants ----------------
__device__ __constant__ float c_DL[8] = {
    -0.010597401784997278f, 0.032883011666982945f, 0.030841381835986965f,
    -0.18703481171888114f, -0.02798376941698385f, 0.6308807679295904f,
    0.7148465705525415f, 0.23037781330885523f};
__device__ __constant__ float c_DH[8] = {
    -0.23037781330885523f, 0.7148465705525415f, -0.6308807679295904f,
    -0.02798376941698385f, 0.18703481171888114f, 0.030841381835986965f,
    -0.032883011666982945f, -0.010597401784997278f};
__device__ __constant__ float c_RL[8] = {
    0.23037781330885523f, 0.7148465705525415f, 0.6308807679295904f,
    -0.02798376941698385f, -0.18703481171888114f, 0.030841381835986965f,
    0.032883011666982945f, -0.010597401784997278f};
__device__ __constant__ float c_RH[8] = {
    -0.010597401784997278f, -0.032883011666982945f, 0.030841381835986965f,
    0.18703481171888114f, -0.02798376941698385f, -0.6308807679295904f,
    0.7148465705525415f, -0.23037781330885523f};

__device__ __forceinline__ float bflo(uint32_t u) { return __uint_as_float(u << 16); }
__device__ __forceinline__ float bfhi(uint32_t u) { return __uint_as_float(u & 0xffff0000u); }
__device__ __forceinline__ float bfu(unsigned short u) { return __uint_as_float(((uint32_t)u) << 16); }
__device__ __forceinline__ short f2bs(float f) {
  __hip_bfloat16 h = __float2bfloat16(f);
  return *reinterpret_cast<short*>(&h);
}

__device__ __forceinline__ int reflect_idx(int t, int n) {
  if (t < 0) t = -1 - t;
  if (t >= n) t = 2 * n - 1 - t;
  return t;
}

// Row strides (padded for aligned vector access)
#define S1R 4100
#define S2R 2056

// ---------------- Weight transpose: w[i][o][p] -> wt[p][i*64+o]
__global__ __launch_bounds__(256) void k_wT(const float* __restrict__ w1,
                                            const float* __restrict__ w2,
                                            float* __restrict__ wt1,
                                            float* __restrict__ wt2) {
  const float* w = blockIdx.z ? w2 : w1;
  float* wt = blockIdx.z ? wt2 : wt1;
  const int io0 = blockIdx.x * 64;
  const int p0 = blockIdx.y * 64;
  const int pw = min(64, 518 - p0);
  const int tid = threadIdx.x;
  __shared__ float ts[64 * 65];
  for (int idx = tid; idx < 64 * 64; idx += 256) {
    int row = idx >> 6, col = idx & 63;
    if (col < pw) ts[row * 65 + col] = w[(size_t)(io0 + row) * 518 + p0 + col];
  }
  __syncthreads();
  for (int idx = tid; idx < 64 * 64; idx += 256) {
    int pl = idx >> 6, io = idx & 63;
    if (pl < pw) wt[(size_t)(p0 + pl) * 4096 + io0 + io] = ts[io * 65 + pl];
  }
}

// ---------------- Level-1 DWT: x (B,N,C) fp32 -> a1,d1 (B*C, stride 4100) bf16
#define NT1 134
#define XTS 138
__global__ __launch_bounds__(256) void k_dwt_first(const float* __restrict__ x,
                                                   __hip_bfloat16* __restrict__ outa,
                                                   __hip_bfloat16* __restrict__ outd) {
  const int b = blockIdx.y;
  const int k0 = blockIdx.x * 64;
  const int tid = threadIdx.x;
  __shared__ float xs[64 * XTS];  // xs[c][nrow]

  const float4* x4 = (const float4*)x;
  for (int idx = tid; idx < NT1 * 16; idx += 256) {
    int nl = idx >> 4, cq = idx & 15;
    int t = 2 * k0 - 6 + nl;
    int n = reflect_idx(t, 8192);
    float4 v = x4[((size_t)b * 8192 + n) * 16 + cq];
    xs[(4 * cq + 0) * XTS + nl] = v.x;
    xs[(4 * cq + 1) * XTS + nl] = v.y;
    xs[(4 * cq + 2) * XTS + nl] = v.z;
    xs[(4 * cq + 3) * XTS + nl] = v.w;
  }
  __syncthreads();

  const int kk = tid & 63;
  const int k = k0 + kk;
  if (k >= 4099) return;
  for (int c = (tid >> 6); c < 64; c += 4) {
    const float2* p = (const float2*)&xs[c * XTS + 2 * kk];
    float2 p0 = p[0], p1 = p[1], p2 = p[2], p3 = p[3];
    float lo = c_DL[0] * p3.y + c_DL[1] * p3.x + c_DL[2] * p2.y + c_DL[3] * p2.x +
               c_DL[4] * p1.y + c_DL[5] * p1.x + c_DL[6] * p0.y + c_DL[7] * p0.x;
    float hi = c_DH[0] * p3.y + c_DH[1] * p3.x + c_DH[2] * p2.y + c_DH[3] * p2.x +
               c_DH[4] * p1.y + c_DH[5] * p1.x + c_DH[6] * p0.y + c_DH[7] * p0.x;
    size_t s = (size_t)b * 64 + c;
    outa[s * S1R + k] = __float2bfloat16(lo);
    outd[s * S1R + k] = __float2bfloat16(hi);
  }
}

// ---------------- Fused analysis levels 2..4, one row per block
// Level-4 outputs written TRANSPOSED: a4t[k*2048 + s], s = i*32 + b.
__global__ __launch_bounds__(256) void k_ana234(const __hip_bfloat16* __restrict__ a1,
                                                __hip_bfloat16* __restrict__ d2o,
                                                float* __restrict__ d3o,
                                                float* __restrict__ a4o,
                                                float* __restrict__ d4o) {
  const int bid = blockIdx.x;
  const int s = (bid & 7) * 256 + (bid >> 3);  // bijective, XCD-contiguous s-range
  const int i_ch = s >> 5;
  const int bb = s & 31;
  const int r = bb * 64 + i_ch;
  const int tid = threadIdx.x;
  __shared__ float s1[4100];
  __shared__ float s2[2054];
  __shared__ float s3[1032];

  const uint2* row2 = (const uint2*)(a1 + (size_t)r * S1R);
  for (int i = tid; i < 1025; i += 256) {
    uint2 u = row2[i];
    int e = 4 * i;
    s1[e] = bflo(u.x); s1[e + 1] = bfhi(u.x);
    s1[e + 2] = bflo(u.y); s1[e + 3] = bfhi(u.y);
  }
  __syncthreads();

  // level 2: n=4099 -> m=2053
  for (int k = tid; k < 2053; k += 256) {
    float lo = 0.f, hi = 0.f;
    if (k >= 3 && k <= 2048) {
      const float2* p = (const float2*)&s1[2 * k - 6];
      float2 v0 = p[0], v1 = p[1], v2 = p[2], v3 = p[3];
      lo = c_RL[0]*v0.x + c_RL[1]*v0.y + c_RL[2]*v1.x + c_RL[3]*v1.y +
           c_RL[4]*v2.x + c_RL[5]*v2.y + c_RL[6]*v3.x + c_RL[7]*v3.y;
      hi = c_RH[0]*v0.x + c_RH[1]*v0.y + c_RH[2]*v1.x + c_RH[3]*v1.y +
           c_RH[4]*v2.x + c_RH[5]*v2.y + c_RH[6]*v3.x + c_RH[7]*v3.y;
    } else {
#pragma unroll
      for (int j = 0; j < 8; ++j) {
        float v = s1[reflect_idx(2 * k + 1 - j, 4099)];
        lo += c_DL[j] * v; hi += c_DH[j] * v;
      }
    }
    d2o[(size_t)r * S2R + k] = __float2bfloat16(hi);
    s2[k] = lo;
  }
  __syncthreads();

  // level 3: n=2053 -> m=1030
  for (int k = tid; k < 1030; k += 256) {
    float lo = 0.f, hi = 0.f;
    if (k >= 3 && k <= 1025) {
      const float2* p = (const float2*)&s2[2 * k - 6];
      float2 v0 = p[0], v1 = p[1], v2 = p[2], v3 = p[3];
      lo = c_RL[0]*v0.x + c_RL[1]*v0.y + c_RL[2]*v1.x + c_RL[3]*v1.y +
           c_RL[4]*v2.x + c_RL[5]*v2.y + c_RL[6]*v3.x + c_RL[7]*v3.y;
      hi = c_RH[0]*v0.x + c_RH[1]*v0.y + c_RH[2]*v1.x + c_RH[3]*v1.y +
           c_RH[4]*v2.x + c_RH[5]*v2.y + c_RH[6]*v3.x + c_RH[7]*v3.y;
    } else {
#pragma unroll
      for (int j = 0; j < 8; ++j) {
        float v = s2[reflect_idx(2 * k + 1 - j, 2053)];
        lo += c_DL[j] * v; hi += c_DH[j] * v;
      }
    }
    d3o[(size_t)r * 1030 + k] = hi;
    s3[k] = lo;
  }
  __syncthreads();

  // level 4: n=1030 -> m=518, transposed scatter (merged in per-XCD L2)
  for (int k = tid; k < 518; k += 256) {
    float lo = 0.f, hi = 0.f;
    if (k >= 3 && k <= 514) {
      const float2* p = (const float2*)&s3[2 * k - 6];
      float2 v0 = p[0], v1 = p[1], v2 = p[2], v3 = p[3];
      lo = c_RL[0]*v0.x + c_RL[1]*v0.y + c_RL[2]*v1.x + c_RL[3]*v1.y +
           c_RL[4]*v2.x + c_RL[5]*v2.y + c_RL[6]*v3.x + c_RL[7]*v3.y;
      hi = c_RH[0]*v0.x + c_RH[1]*v0.y + c_RH[2]*v1.x + c_RH[3]*v1.y +
           c_RH[4]*v2.x + c_RH[5]*v2.y + c_RH[6]*v3.x + c_RH[7]*v3.y;
    } else {
#pragma unroll
      for (int j = 0; j < 8; ++j) {
        float v = s3[reflect_idx(2 * k + 1 - j, 1030)];
        lo += c_DL[j] * v; hi += c_DH[j] * v;
      }
    }
    a4o[(size_t)k * 2048 + s] = lo;
    d4o[(size_t)k * 2048 + s] = hi;
  }
}

// ---------------- Channel mixing: one block per (p, a-or-d), staging contiguous.
__global__ __launch_bounds__(256) void k_mix_pc(const float* __restrict__ wt1,
                                                const float* __restrict__ wt2,
                                                const float* __restrict__ a4t,
                                                const float* __restrict__ d4t,
                                                float* __restrict__ am,
                                                float* __restrict__ dm) {
  const int bx = blockIdx.x;
  const int xcd = bx & 7;
  const int j = bx >> 3;
  const int p = (xcd < 6) ? (xcd * 65 + j) : (390 + (xcd - 6) * 64 + j);

  const float* w = blockIdx.y ? wt2 : wt1;
  const float* act = blockIdx.y ? d4t : a4t;
  float* outp = blockIdx.y ? dm : am;

  __shared__ float ws[4096];   // ws[i*64+o]
  __shared__ float as_[2048];  // as_[i*32+b]
  const int tid = threadIdx.x;

  const float4* wg = (const float4*)(w + (size_t)p * 4096);
  const float4* ag = (const float4*)(act + (size_t)p * 2048);
  float4* ws4 = (float4*)ws;
  float4* as4 = (float4*)as_;
  for (int t = tid; t < 1024; t += 256) ws4[t] = wg[t];
  for (int t = tid; t < 512; t += 256) as4[t] = ag[t];
  __syncthreads();

  const int o0 = (tid & 15) * 4;
  const int bq = tid >> 4;
  floatx4 acc0 = {0.f, 0.f, 0.f, 0.f}, acc1 = {0.f, 0.f, 0.f, 0.f};

#pragma unroll 8
  for (int i = 0; i < 64; ++i) {
    floatx4 wv = *(const floatx4*)&ws[i * 64 + o0];
    float a0 = as_[i * 32 + bq];
    float a1 = as_[i * 32 + bq + 16];
#pragma unroll
    for (int q = 0; q < 4; ++q) {
      acc0[q] += a0 * wv[q];
      acc1[q] += a1 * wv[q];
    }
  }

#pragma unroll
  for (int q = 0; q < 4; ++q) {
    outp[(size_t)(bq * 64 + o0 + q) * 518 + p] = acc0[q];
    outp[(size_t)((bq + 16) * 64 + o0 + q) * 518 + p] = acc1[q];
  }
}

// ---------------- Fused synthesis levels 4->3->2: writes recon1 (bf16) directly.
__global__ __launch_bounds__(256) void k_syn(const float* __restrict__ a4m,
                                             const float* __restrict__ d4m,
                                             const float* __restrict__ d3,
                                             const __hip_bfloat16* __restrict__ d2,
                                             __hip_bfloat16* __restrict__ r1out) {
  const int r = blockIdx.x;
  const int tid = threadIdx.x;
  __shared__ float sa[518], sd[518], s3d[1030], r3[1030], r2[2053];
  __shared__ unsigned short d2s[2056];
  for (int i = tid; i < 518; i += 256) {
    sa[i] = a4m[(size_t)r * 518 + i];
    sd[i] = d4m[(size_t)r * 518 + i];
  }
  for (int i = tid; i < 1030; i += 256) s3d[i] = d3[(size_t)r * 1030 + i];
  {
    const ushort4* p2 = (const ushort4*)(d2 + (size_t)r * S2R);
    for (int i = tid; i < 514; i += 256) {
      ushort4 u = p2[i];
      int e = 4 * i;
      d2s[e] = u.x; d2s[e + 1] = u.y; d2s[e + 2] = u.z; d2s[e + 3] = u.w;
    }
  }
  __syncthreads();
  // level 4 -> r3 (1030)
  for (int s = tid; s < 1030; s += 256) {
    int u = s >> 1, par = s & 1;
    float acc = 0.f;
#pragma unroll
    for (int t = 0; t < 4; ++t) {
      int i = u + 3 - t;
      float fl = par ? c_RL[2 * t + 1] : c_RL[2 * t];
      float fh = par ? c_RH[2 * t + 1] : c_RH[2 * t];
      acc += fl * sa[i] + fh * sd[i];
    }
    r3[s] = acc;
  }
  __syncthreads();
  // level 3 -> r2 (2053), fp32 in LDS
  for (int s = tid; s < 2053; s += 256) {
    int u = s >> 1, par = s & 1;
    float acc = 0.f;
#pragma unroll
    for (int t = 0; t < 4; ++t) {
      int i = u + 3 - t;
      float fl = par ? c_RL[2 * t + 1] : c_RL[2 * t];
      float fh = par ? c_RH[2 * t + 1] : c_RH[2 * t];
      acc += fl * r3[i] + fh * s3d[i];
    }
    r2[s] = acc;
  }
  __syncthreads();
  // level 2 -> r1 (4099), bf16 to global
  for (int s = tid; s < 4099; s += 256) {
    int u = s >> 1, par = s & 1;
    float acc = 0.f;
#pragma unroll
    for (int t = 0; t < 4; ++t) {
      int i = u + 3 - t;
      float fl = par ? c_RL[2 * t + 1] : c_RL[2 * t];
      float fh = par ? c_RH[2 * t + 1] : c_RH[2 * t];
      acc += fl * r2[i] + fh * bfu(d2s[i]);
    }
    r1out[(size_t)r * S1R + s] = __float2bfloat16(acc);
  }
}

// ---------------- Epilogue: MFMA dense shortcut + final IDWT + bias + mish -> fp32
// block 256 (4 waves), tile 64n x 64o, grid (128, 32).
// v2: (a) x loads issued at kernel entry (latency hides under LDS staging),
//     (b) IDWT coeffs pair-shared: even/odd outputs of one u-window reuse the
//         same 4+4 LDS reads -> wv LDS reads halved (128 -> 64 per thread).
#define RAS 68
__global__ __launch_bounds__(256) void k_epilogue(const __hip_bfloat16* __restrict__ r1,
                                                  const __hip_bfloat16* __restrict__ dd1,
                                                  const float* __restrict__ x,
                                                  const float* __restrict__ dk,
                                                  const float* __restrict__ bias,
                                                  float* __restrict__ out) {
  const int b = blockIdx.y;
  const int n0 = blockIdx.x * 64;
  const int u0 = n0 >> 1;
  const int tid = threadIdx.x;
  const int lane = tid & 63;
  const int w = tid >> 6;

  // ---- issue x loads EARLY (consumed after the barrier; ~900cy HBM latency
  //      overlaps the Ktf/ra/rd staging below) ----
  const int m16 = lane & 15;
  const int kq = (lane >> 4) * 8;
  const int nrow = w * 16 + m16;
  const float* xrow = x + ((size_t)b * 8192 + n0 + nrow) * 64;
  float4 xa0 = *(const float4*)(xrow + kq);
  float4 xb0 = *(const float4*)(xrow + kq + 4);
  float4 xa1 = *(const float4*)(xrow + 32 + kq);
  float4 xb1 = *(const float4*)(xrow + 32 + kq + 4);

  __shared__ __hip_bfloat16 Ktf[4096];    // fragment-ordered K^T
  __shared__ unsigned short ra[36 * RAS];  // r1 window, raw bf16 bits
  __shared__ unsigned short rd[36 * RAS];  // d1 window, raw bf16 bits

  // stage Ktf: thread t owns column o=t&63; (ks,hi) slot = (t>>6)+4*it.
  {
    int o = tid & 63;
    int ot = o >> 4, m16o = o & 15;
    for (int it = 0; it < 2; ++it) {
      int slot = (tid >> 6) + 4 * it;
      int ks = slot >> 2, hi = slot & 3;
      int c0 = ks * 32 + hi * 8;
      short8 f;
#pragma unroll
      for (int kq2 = 0; kq2 < 8; ++kq2)
        f[kq2] = f2bs(dk[(size_t)(c0 + kq2) * 64 + o]);
      *(short8*)&Ktf[((ot * 2 + ks) * 64 + hi * 16 + m16o) * 8] = f;
    }
  }
  // stage ra/rd (35 coeffs x 64 channels), vectorized ushort4 (8B) loads, raw bits.
  {
    int o2 = tid >> 2;
    const ushort4* pr4 = (const ushort4*)(r1 + (size_t)(b * 64 + o2) * S1R + u0);
    const ushort4* pd4 = (const ushort4*)(dd1 + (size_t)(b * 64 + o2) * S1R + u0);
    for (int q = tid & 3; q < 9; q += 4) {
      ushort4 v = pr4[q];
      int i0 = 4 * q;
      ra[(i0 + 0) * RAS + o2] = v.x;
      ra[(i0 + 1) * RAS + o2] = v.y;
      ra[(i0 + 2) * RAS + o2] = v.z;
      ra[(i0 + 3) * RAS + o2] = v.w;
      ushort4 d = pd4[q];
      rd[(i0 + 0) * RAS + o2] = d.x;
      rd[(i0 + 1) * RAS + o2] = d.y;
      rd[(i0 + 2) * RAS + o2] = d.z;
      rd[(i0 + 3) * RAS + o2] = d.w;
    }
  }
  __syncthreads();

  floatx4 acc[4];
#pragma unroll
  for (int ot = 0; ot < 4; ++ot) acc[ot] = (floatx4){0.f, 0.f, 0.f, 0.f};

  {
    short8 af0, af1;
    af0[0] = f2bs(xa0.x); af0[1] = f2bs(xa0.y); af0[2] = f2bs(xa0.z); af0[3] = f2bs(xa0.w);
    af0[4] = f2bs(xb0.x); af0[5] = f2bs(xb0.y); af0[6] = f2bs(xb0.z); af0[7] = f2bs(xb0.w);
    af1[0] = f2bs(xa1.x); af1[1] = f2bs(xa1.y); af1[2] = f2bs(xa1.z); af1[3] = f2bs(xa1.w);
    af1[4] = f2bs(xb1.x); af1[5] = f2bs(xb1.y); af1[6] = f2bs(xb1.z); af1[7] = f2bs(xb1.w);
#pragma unroll
    for (int ot = 0; ot < 4; ++ot) {
      short8 bf0 = *(const short8*)&Ktf[((ot * 2 + 0) * 64 + lane) * 8];
      acc[ot] = __builtin_amdgcn_mfma_f32_16x16x32_bf16(af0, bf0, acc[ot], 0, 0, 0);
      short8 bf1 = *(const short8*)&Ktf[((ot * 2 + 1) * 64 + lane) * 8];
      acc[ot] = __builtin_amdgcn_mfma_f32_16x16x32_bf16(af1, bf1, acc[ot], 0, 0, 0);
    }
  }

  // epilogue: C/D layout col=lane&15 (o), row=(lane>>4)*4+reg (n)
  // pair-shared IDWT: rg={2pr, 2pr+1} share the same 4-coeff window ul+pr.
  const int rbase = (lane >> 4) * 4;
  const int ul0 = (w * 16 + rbase) >> 1;
#pragma unroll
  for (int ot = 0; ot < 4; ++ot) {
    int o_loc = ot * 16 + m16;
    float bo = bias[o_loc];
#pragma unroll
    for (int pr = 0; pr < 2; ++pr) {
      int ul = ul0 + pr;
      float av[4], dv[4];
#pragma unroll
      for (int t = 0; t < 4; ++t) {
        int i = ul + 3 - t;
        av[t] = bfu(ra[i * RAS + o_loc]);
        dv[t] = bfu(rd[i * RAS + o_loc]);
      }
      float wv_e = 0.f, wv_o = 0.f;
#pragma unroll
      for (int t = 0; t < 4; ++t) {
        wv_e += c_RL[2 * t] * av[t] + c_RH[2 * t] * dv[t];
        wv_o += c_RL[2 * t + 1] * av[t] + c_RH[2 * t + 1] * dv[t];
      }
#pragma unroll
      for (int par = 0; par < 2; ++par) {
        int rg = 2 * pr + par;
        int n_loc = w * 16 + rbase + rg;
        float v = acc[ot][rg] + (par ? wv_o : wv_e) + bo;
        float e = __expf(fminf(v, 15.f));
        float num = e * (e + 2.f);
        float mm = (v > 15.f) ? v : v * (num / (num + 2.f));
        __builtin_nontemporal_store(mm, &out[((size_t)b * 8192 + n0 + n_loc) * 64 + o_loc]);
      }
    }
  }
}

// ---------------- host ----------------
extern "C" void kernel_launch(void* const* d_in, const int* in_sizes, int n_in,
                              void* d_out, int out_size, void* d_ws, size_t ws_size,
                              hipStream_t stream) {
  const float* x    = (const float*)d_in[0];
  const float* w1   = (const float*)d_in[1];
  const float* w2   = (const float*)d_in[2];
  const float* dk   = (const float*)d_in[3];
  const float* bias = (const float*)d_in[4];
  float* out = (float*)d_out;

  const size_t R = 2048;

  float* wf = (float*)d_ws;
  float* d3f = wf; wf += R * 1030;
  float* a4t = wf; wf += R * 518;   // transposed: [p][i*32+b]
  float* d4t = wf; wf += R * 518;
  float* a4m = wf; wf += R * 518;   // mix outputs, row-major (b*64+o)
  float* d4m = wf; wf += R * 518;
  float* wt1 = wf; wf += (size_t)518 * 4096;  // transposed weights [p][i*64+o]
  float* wt2 = wf; wf += (size_t)518 * 4096;
  __hip_bfloat16* wb = (__hip_bfloat16*)wf;
  __hip_bfloat16* a1b = wb; wb += R * S1R;  // analysis a1, later recon1
  __hip_bfloat16* d1b = wb; wb += R * S1R;
  __hip_bfloat16* d2b = wb; wb += R * S2R;

  k_wT<<<dim3(64, 9, 2), 256, 0, stream>>>(w1, w2, wt1, wt2);
  k_dwt_first<<<dim3(65, 32), 256, 0, stream>>>(x, a1b, d1b);
  k_ana234<<<dim3(2048), 256, 0, stream>>>(a1b, d2b, d3f, a4t, d4t);
  k_mix_pc<<<dim3(518, 2), 256, 0, stream>>>(wt1, wt2, a4t, d4t, a4m, d4m);
  k_syn<<<dim3(2048), 256, 0, stream>>>(a4m, d4m, d3f, d2b, a1b);
  k_epilogue<<<dim3(128, 32), 256, 0, stream>>>(a1b, d1b, x, dk, bias, out);
}